// Round 1
// baseline (944.545 us; speedup 1.0000x reference)
//
#include <hip/hip_runtime.h>
#include <hip/hip_fp16.h>

#define F_IN  128
#define F_HID 8
#define F_OUT 16

#define SBSH  9                 // coarse bucket = 512 consecutive dst nodes
#define SBW   (1 << SBSH)
#define MAXB  400               // supports N <= 204800
#define BIN_CAP  32             // LDS entries per bucket (stage_bin)
#define FLUSH_G  16             // flush granularity (16 ints = 64B line)
#define TILE_E   2048           // stage entries per LDS tile in agg kernels

// edge_index arrives as int32 [2][E].
// Session laws: (1) scattered 4B global stores/atomics cost ~64B cross-XCD
// writeback -> all scatters are LDS-write-combined contiguous runs;
// (2) gather/scatter kernels need lots of in-flight loads (TLP or unroll);
// (3) fp16 g (3.2MB) is L2-resident -> gathers are ~200cy L2 hits;
// (4) per-node epilogues fuse into aggregates; (5) bucket regions are
// FIXED-CAP (avg+6%) so no counting pre-pass.
// R1 restructure: stage[] is already dst-bucket-grouped -> CSR build was
// pure overhead. Aggregation is now EDGE-parallel per bucket into an LDS
// fp32 accumulator (8 lanes/edge, lane=feature): coalesced 16B gathers,
// ds_add_f32 with <=2-way bank aliasing (free), zero divergence, stage
// streamed via double-buffered global_load_lds.

typedef float f32x4 __attribute__((ext_vector_type(4)));

__global__ void init_gcur(int* __restrict__ gcur, int cap, int B) {
    int b = blockIdx.x * blockDim.x + threadIdx.x;
    if (b < B) gcur[b] = b * cap;
}

// LDS write-combined binning: stage[...] = (src<<9)|(dst&511), bucket-grouped.
// 512 threads/block; int4 edge loads; bin_buf slots swizzled (pos+b)&31.
__global__ __launch_bounds__(512) void stage_bin(const int* __restrict__ ei,
                                                 int* __restrict__ gcur,
                                                 int* __restrict__ stage,
                                                 int E, int B, int per_block) {
    __shared__ int bin_cnt[MAXB];
    __shared__ int bin_buf[MAXB * BIN_CAP];   // ~51KB
    for (int i = threadIdx.x; i < B; i += blockDim.x) bin_cnt[i] = 0;
    __syncthreads();
    const bool vec = ((E & 3) == 0);
    int base = blockIdx.x * per_block;
    int end  = min(E, base + per_block);
    for (int it = base; it < end; it += (int)blockDim.x * 4) {
        int e = it + (int)threadIdx.x * 4;
        int sv[4], dv[4], m4 = 0;
        if (vec && e + 3 < end) {
            int4 s4 = *(const int4*)(ei + e);
            int4 d4 = *(const int4*)(ei + E + e);
            sv[0] = s4.x; sv[1] = s4.y; sv[2] = s4.z; sv[3] = s4.w;
            dv[0] = d4.x; dv[1] = d4.y; dv[2] = d4.z; dv[3] = d4.w;
            m4 = 4;
        } else {
            for (int q = 0; e + q < end && q < 4; q++) { sv[q] = ei[e + q]; dv[q] = ei[E + e + q]; m4++; }
        }
        for (int q = 0; q < m4; q++) {
            int b   = dv[q] >> SBSH;
            int val = (sv[q] << SBSH) | (dv[q] & (SBW - 1));
            int pos = atomicAdd(&bin_cnt[b], 1);
            if (pos < BIN_CAP) {
                bin_buf[b * BIN_CAP + ((pos + b) & (BIN_CAP - 1))] = val;
            } else {                                  // overflow (rare): direct store
                int gp = atomicAdd(&gcur[b], 1);
                stage[gp] = val;
            }
        }
        __syncthreads();
        for (int b2 = threadIdx.x; b2 < B; b2 += blockDim.x) {
            int c = min(bin_cnt[b2], BIN_CAP);
            if (c >= FLUSH_G) {
                int m = c & ~(FLUSH_G - 1);
                int r = atomicAdd(&gcur[b2], m);
                for (int k = 0; k < m; k++)
                    stage[r + k] = bin_buf[b2 * BIN_CAP + ((k + b2) & (BIN_CAP - 1))];   // contiguous run
                for (int k = m; k < c; k++)
                    bin_buf[b2 * BIN_CAP + ((k - m + b2) & (BIN_CAP - 1))] =
                        bin_buf[b2 * BIN_CAP + ((k + b2) & (BIN_CAP - 1))];
                bin_cnt[b2] = c - m;
            } else {
                bin_cnt[b2] = c;
            }
        }
        __syncthreads();
    }
    for (int b2 = threadIdx.x; b2 < B; b2 += blockDim.x) {   // final flush
        int c = min(bin_cnt[b2], BIN_CAP);
        if (c > 0) {
            int r = atomicAdd(&gcur[b2], c);
            for (int k = 0; k < c; k++)
                stage[r + k] = bin_buf[b2 * BIN_CAP + ((k + b2) & (BIN_CAP - 1))];
        }
    }
}

// ---------------- per-bucket degree histogram -> dis ----------------
// (replaces scatter_csr: dis is the only remaining consumer of the degree)
__global__ __launch_bounds__(512) void degree_dis(const int* __restrict__ stage,
                                                  const int* __restrict__ gcur,
                                                  int cap, float* __restrict__ dis, int n) {
    __shared__ int s0[SBW];
    int b = blockIdx.x, i = threadIdx.x;
    s0[i] = 0;
    __syncthreads();
    int base = b * cap;
    int num  = min(gcur[b] - base, cap);
    int numv = num & ~(TILE_E - 1);                  // int4-vectorized bulk
    for (int k = i * 4; k < numv; k += TILE_E) {
        int4 v = *(const int4*)(stage + base + k);
        atomicAdd(&s0[v.x & (SBW - 1)], 1);
        atomicAdd(&s0[v.y & (SBW - 1)], 1);
        atomicAdd(&s0[v.z & (SBW - 1)], 1);
        atomicAdd(&s0[v.w & (SBW - 1)], 1);
    }
    for (int k = numv + i; k < num; k += 512)
        atomicAdd(&s0[stage[base + k] & (SBW - 1)], 1);
    __syncthreads();
    int node = (b << SBSH) + i;
    if (node < n) dis[node] = rsqrtf((float)(s0[i] + 1));   // +1 self-loop
}

// ---------------- layer-1 GEMM: g1 = (x @ W1) * dis, stored fp16 ----------------
// 8 lanes/node: each group reads 128B contiguous per step (64B lines fully
// consumed per instruction, no L1-reuse dependence); W1 staged TRANSPOSED in
// LDS (bank = j*4+q, conflict-free); shfl_xor width-8 reduce; lane0 16B store.
__global__ __launch_bounds__(256) void gemm1(const float* __restrict__ x,
                                             const float* __restrict__ W1,
                                             const float* __restrict__ dis,
                                             __half* __restrict__ g1, int n) {
    __shared__ float w2[F_HID * F_IN];   // [f][k] transposed, 4KB
    for (int i = threadIdx.x; i < F_HID * F_IN; i += blockDim.x) {
        int f = i >> 7, k = i & (F_IN - 1);
        w2[i] = W1[k * F_HID + f];
    }
    __syncthreads();
    int t = blockIdx.x * blockDim.x + threadIdx.x;
    int node = t >> 3, l = t & 7;
    if (node >= n) return;
    const f32x4* xr = (const f32x4*)(x + (size_t)node * F_IN);
    float acc[F_HID];
#pragma unroll
    for (int f = 0; f < F_HID; f++) acc[f] = 0.0f;
#pragma unroll
    for (int it = 0; it < 4; it++) {
        int j = l + it * 8;                       // this lane's float4 index
        f32x4 v = xr[j];
#pragma unroll
        for (int f = 0; f < F_HID; f++) {
            const float* wf = &w2[f * F_IN + j * 4];
            acc[f] += v[0] * wf[0] + v[1] * wf[1] + v[2] * wf[2] + v[3] * wf[3];
        }
    }
#pragma unroll
    for (int f = 0; f < F_HID; f++) {             // reduce across the 8 lanes
        acc[f] += __shfl_xor(acc[f], 1);
        acc[f] += __shfl_xor(acc[f], 2);
        acc[f] += __shfl_xor(acc[f], 4);
    }
    if (l == 0) {
        float d = dis[node];
        __half2 h[4];
#pragma unroll
        for (int p = 0; p < 4; p++) h[p] = __floats2half2_rn(acc[2 * p] * d, acc[2 * p + 1] * d);
        *(uint4*)(g1 + (size_t)node * F_HID) = *(uint4*)h;   // 16B store
    }
}

// ---------------- edge-parallel bucket accumulation core ----------------
__device__ __forceinline__ void gll16(const int* gsrc, int* ldst) {
    __builtin_amdgcn_global_load_lds(
        (const __attribute__((address_space(1))) void*)gsrc,
        (__attribute__((address_space(3))) void*)ldst, 16, 0, 0);
}

__device__ __forceinline__ void lds_faddx(float* p, float v) {
    (void)__hip_atomic_fetch_add(p, v, __ATOMIC_RELAXED, __HIP_MEMORY_SCOPE_WORKGROUP);
}

// stage a TILE_E-entry tile into LDS: dest = wave-uniform base + lane*16 (linear,
// matches gsrc lane order). stage has TILE_E ints of slack at the end, so the
// final partial tile may read past the bucket region (garbage never processed).
__device__ __forceinline__ void stage_tile(const int* __restrict__ stage, int base,
                                           int t, int* lbuf, int tid) {
    gll16(stage + base + t * TILE_E + tid * 4, lbuf + ((tid >> 6) << 8));
}

// acc[512][8] fp32 in LDS. 8 lanes/edge (lane = feature): gather is one
// coalesced 16B read per group; ds_add bank = (dst&3)*8+f -> <=2-way aliasing
// across a wave's 8 edge groups (free, m136). Double-buffered stage tiles.
__device__ __forceinline__ void bucket_accumulate(const int* __restrict__ stage,
                                                  int base, int num,
                                                  const __half* __restrict__ gin,
                                                  float* acc, int* ebuf, int tid) {
    int ntile = (num + TILE_E - 1) / TILE_E;
    if (ntile > 0) stage_tile(stage, base, 0, ebuf, tid);
    int g = tid >> 3, f = tid & 7;
    for (int t = 0; t < ntile; t++) {
        int cur = t & 1;
        __syncthreads();                          // tile t landed (barrier drains vmcnt)
        if (t + 1 < ntile) stage_tile(stage, base, t + 1, ebuf + ((cur ^ 1) * TILE_E), tid);
        int cnt_t = min(TILE_E, num - t * TILE_E);
        const int* eb = ebuf + cur * TILE_E;
        int k = g;
        for (; k + 192 < cnt_t; k += 256) {       // 4 independent gathers in flight
            int v0 = eb[k], v1 = eb[k + 64], v2 = eb[k + 128], v3 = eb[k + 192];
            float a0 = __half2float(gin[(size_t)((unsigned)v0 >> SBSH) * F_HID + f]);
            float a1 = __half2float(gin[(size_t)((unsigned)v1 >> SBSH) * F_HID + f]);
            float a2 = __half2float(gin[(size_t)((unsigned)v2 >> SBSH) * F_HID + f]);
            float a3 = __half2float(gin[(size_t)((unsigned)v3 >> SBSH) * F_HID + f]);
            lds_faddx(&acc[(v0 & (SBW - 1)) * F_HID + f], a0);
            lds_faddx(&acc[(v1 & (SBW - 1)) * F_HID + f], a1);
            lds_faddx(&acc[(v2 & (SBW - 1)) * F_HID + f], a2);
            lds_faddx(&acc[(v3 & (SBW - 1)) * F_HID + f], a3);
        }
        for (; k < cnt_t; k += 64) {
            int v = eb[k];
            float a = __half2float(gin[(size_t)((unsigned)v >> SBSH) * F_HID + f]);
            lds_faddx(&acc[(v & (SBW - 1)) * F_HID + f], a);
        }
    }
    __syncthreads();                              // all ds_adds visible to epilogue
}

// ---------------- layer-1 aggregate + bias + ReLU + xdis -> g2 (fp16) ----------------
__global__ __launch_bounds__(512) void agg1(const int* __restrict__ stage,
                                            const int* __restrict__ gcur, int cap,
                                            const float* __restrict__ dis,
                                            const float* __restrict__ b1,
                                            const __half* __restrict__ gin,
                                            __half* __restrict__ gout, int n) {
    __shared__ __align__(16) float acc[SBW * F_HID];    // 16KB
    __shared__ __align__(16) int   ebuf[2 * TILE_E];    // 16KB
    __shared__ float bb[F_HID];
    int tid = threadIdx.x, b = blockIdx.x;
    if (tid < F_HID) bb[tid] = b1[tid];
#pragma unroll
    for (int q = 0; q < (SBW * F_HID) / 512; q++) acc[tid + q * 512] = 0.0f;
    int base = b * cap;
    int num  = min(gcur[b] - base, cap);
    bucket_accumulate(stage, base, num, gin, acc, ebuf, tid);
    int node = (b << SBSH) + tid;                 // thread-per-node epilogue
    if (node < n) {
        float d = dis[node];
        uint4 hv = *(const uint4*)(gin + (size_t)node * F_HID);   // self-loop
        __half hbuf[F_HID]; *(uint4*)hbuf = hv;
        __half ob[F_HID];
#pragma unroll
        for (int f2 = 0; f2 < F_HID; f2++) {
            float s = acc[tid * F_HID + f2] + __half2float(hbuf[f2]);
            ob[f2] = __float2half(fmaxf(fmaf(d, s, bb[f2]), 0.0f) * d);
        }
        *(uint4*)(gout + (size_t)node * F_HID) = *(uint4*)ob;     // 16B coalesced
    }
}

// ---------------- layer-2 aggregate + W2/b2 -> out ----------------
__global__ __launch_bounds__(512) void agg2(const int* __restrict__ stage,
                                            const int* __restrict__ gcur, int cap,
                                            const float* __restrict__ dis,
                                            const float* __restrict__ W2,
                                            const float* __restrict__ b2,
                                            const __half* __restrict__ gin,
                                            float* __restrict__ out, int n) {
    __shared__ __align__(16) float acc[SBW * F_HID];    // 16KB
    __shared__ __align__(16) int   ebuf[2 * TILE_E];    // 16KB
    __shared__ float w[F_HID * F_OUT];
    __shared__ float bb[F_OUT];
    int tid = threadIdx.x, b = blockIdx.x;
    if (tid < F_HID * F_OUT) w[tid] = W2[tid];
    if (tid < F_OUT) bb[tid] = b2[tid];
#pragma unroll
    for (int q = 0; q < (SBW * F_HID) / 512; q++) acc[tid + q * 512] = 0.0f;
    int base = b * cap;
    int num  = min(gcur[b] - base, cap);
    bucket_accumulate(stage, base, num, gin, acc, ebuf, tid);
    int node = (b << SBSH) + tid;
    if (node < n) {
        float d = dis[node];
        uint4 hv = *(const uint4*)(gin + (size_t)node * F_HID);   // self-loop
        __half hbuf[F_HID]; *(uint4*)hbuf = hv;
        float a[F_HID];
#pragma unroll
        for (int f2 = 0; f2 < F_HID; f2++)
            a[f2] = d * (acc[tid * F_HID + f2] + __half2float(hbuf[f2]));
        float o[F_OUT];
#pragma unroll
        for (int oo = 0; oo < F_OUT; oo++) o[oo] = bb[oo];
#pragma unroll
        for (int f2 = 0; f2 < F_HID; f2++)
#pragma unroll
            for (int oo = 0; oo < F_OUT; oo++)
                o[oo] = fmaf(a[f2], w[f2 * F_OUT + oo], o[oo]);
        float4* op = (float4*)(out + (size_t)node * F_OUT);       // 64B coalesced
        op[0] = make_float4(o[0],  o[1],  o[2],  o[3]);
        op[1] = make_float4(o[4],  o[5],  o[6],  o[7]);
        op[2] = make_float4(o[8],  o[9],  o[10], o[11]);
        op[3] = make_float4(o[12], o[13], o[14], o[15]);
    }
}

extern "C" void kernel_launch(void* const* d_in, const int* in_sizes, int n_in,
                              void* d_out, int out_size, void* d_ws, size_t ws_size,
                              hipStream_t stream) {
    const float* x  = (const float*)d_in[0];
    const int*   ei = (const int*)d_in[1];
    const float* W1 = (const float*)d_in[2];
    const float* b1 = (const float*)d_in[3];
    const float* W2 = (const float*)d_in[4];
    const float* b2 = (const float*)d_in[5];
    float* out = (float*)d_out;

    const int N = in_sizes[0] / F_IN;
    const int E = in_sizes[1] / 2;
    const int B = (N + SBW - 1) >> SBSH;   // 391 for N=200000

    // fixed bucket capacity: avg + ~6%, rounded to 256 (≈8 sigma for uniform dst)
    int avg = (E + B - 1) / B;
    int cap = (avg + avg / 16 + 255) & ~255;

    // ws (4B units): stage[B*cap + TILE_E slack] | dis[N] | gA[4N] | gB[4N] | gcur[B]
    int*    stage = (int*)d_ws;
    float*  dis   = (float*)(stage + (size_t)B * cap + TILE_E);
    __half* gA    = (__half*)(dis + N);
    __half* gB    = gA + (size_t)N * F_HID;
    int*    gcur  = (int*)(gB + (size_t)N * F_HID);

    const int BT = 256;

    // stage_bin: 512 threads; per_block multiple of 2048 (int4 x 512 alignment)
    int per_block = ((E + 639) / 640 + 2047) & ~2047;
    int SBLK = (E + per_block - 1) / per_block;

    init_gcur <<<dim3((B + BT - 1) / BT), dim3(BT), 0, stream>>>(gcur, cap, B);
    stage_bin <<<dim3(SBLK), dim3(512), 0, stream>>>(ei, gcur, stage, E, B, per_block);
    degree_dis<<<dim3(B), dim3(512), 0, stream>>>(stage, gcur, cap, dis, N);
    gemm1     <<<dim3(((size_t)N * 8 + BT - 1) / BT), dim3(BT), 0, stream>>>(x, W1, dis, gA, N);
    agg1      <<<dim3(B), dim3(512), 0, stream>>>(stage, gcur, cap, dis, b1, gA, gB, N);
    agg2      <<<dim3(B), dim3(512), 0, stream>>>(stage, gcur, cap, dis, W2, b2, gB, out, N);
}

// Round 2
// 871.300 us; speedup vs baseline: 1.0841x; 1.0841x over previous
//
#include <hip/hip_runtime.h>
#include <hip/hip_fp16.h>

#define F_IN  128
#define F_HID 8
#define F_OUT 16

#define SBSH  9                 // coarse bucket = 512 consecutive dst nodes
#define SBW   (1 << SBSH)
#define MAXB  400               // supports N <= 204800
#define BIN_CAP  32             // LDS entries per bucket (stage_bin)
#define FLUSH_G  16             // flush granularity (16 ints = 64B line)
#define TILE_E   2048           // stage entries per LDS tile in agg kernels
#define SPLIT    4              // blocks per bucket in agg/hist (TLP + balance)

// edge_index arrives as int32 [2][E].
// Session laws: (1) scattered 4B global stores/atomics cost ~64B cross-XCD
// writeback -> scatters are LDS-accumulated, flushed as contiguous runs;
// (2) gather/scatter kernels need lots of in-flight waves;
// (3) fp16 g (3.2MB) is L2-resident -> gathers are ~200cy L2 hits;
// (4) per-node epilogues fuse into elementwise passes; (5) bucket regions are
// FIXED-CAP (avg+6%) so no counting pre-pass.
// R2 lesson: __hip_atomic_fetch_add on a generic float* lowered to a flat/CAS
// atomic on LDS (lane-serialized, agg 350us @ 2.8% VALUBusy). Use plain
// atomicAdd on the __shared__ array -> native ds_add_f32 (R0's scatter_csr
// proved 13M LDS atomicAdds run in ~70us at this geometry).

typedef float f32x4 __attribute__((ext_vector_type(4)));

__global__ void init_k(int* __restrict__ gcur, int cap, int B,
                       int* __restrict__ deg, int N) {
    int t = blockIdx.x * blockDim.x + threadIdx.x;
    if (t < B) gcur[t] = t * cap;
    if (t < N) deg[t] = 0;
}

// LDS write-combined binning: stage[...] = (src<<9)|(dst&511), bucket-grouped.
// 512 threads/block; int4 edge loads; bin_buf slots swizzled (pos+b)&31.
__global__ __launch_bounds__(512) void stage_bin(const int* __restrict__ ei,
                                                 int* __restrict__ gcur,
                                                 int* __restrict__ stage,
                                                 int E, int B, int per_block) {
    __shared__ int bin_cnt[MAXB];
    __shared__ int bin_buf[MAXB * BIN_CAP];   // ~51KB
    for (int i = threadIdx.x; i < B; i += blockDim.x) bin_cnt[i] = 0;
    __syncthreads();
    const bool vec = ((E & 3) == 0);
    int base = blockIdx.x * per_block;
    int end  = min(E, base + per_block);
    for (int it = base; it < end; it += (int)blockDim.x * 4) {
        int e = it + (int)threadIdx.x * 4;
        int sv[4], dv[4], m4 = 0;
        if (vec && e + 3 < end) {
            int4 s4 = *(const int4*)(ei + e);
            int4 d4 = *(const int4*)(ei + E + e);
            sv[0] = s4.x; sv[1] = s4.y; sv[2] = s4.z; sv[3] = s4.w;
            dv[0] = d4.x; dv[1] = d4.y; dv[2] = d4.z; dv[3] = d4.w;
            m4 = 4;
        } else {
            for (int q = 0; e + q < end && q < 4; q++) { sv[q] = ei[e + q]; dv[q] = ei[E + e + q]; m4++; }
        }
        for (int q = 0; q < m4; q++) {
            int b   = dv[q] >> SBSH;
            int val = (sv[q] << SBSH) | (dv[q] & (SBW - 1));
            int pos = atomicAdd(&bin_cnt[b], 1);
            if (pos < BIN_CAP) {
                bin_buf[b * BIN_CAP + ((pos + b) & (BIN_CAP - 1))] = val;
            } else {                                  // overflow (rare): direct store
                int gp = atomicAdd(&gcur[b], 1);
                stage[gp] = val;
            }
        }
        __syncthreads();
        for (int b2 = threadIdx.x; b2 < B; b2 += blockDim.x) {
            int c = min(bin_cnt[b2], BIN_CAP);
            if (c >= FLUSH_G) {
                int m = c & ~(FLUSH_G - 1);
                int r = atomicAdd(&gcur[b2], m);
                for (int k = 0; k < m; k++)
                    stage[r + k] = bin_buf[b2 * BIN_CAP + ((k + b2) & (BIN_CAP - 1))];   // contiguous run
                for (int k = m; k < c; k++)
                    bin_buf[b2 * BIN_CAP + ((k - m + b2) & (BIN_CAP - 1))] =
                        bin_buf[b2 * BIN_CAP + ((k + b2) & (BIN_CAP - 1))];
                bin_cnt[b2] = c - m;
            } else {
                bin_cnt[b2] = c;
            }
        }
        __syncthreads();
    }
    for (int b2 = threadIdx.x; b2 < B; b2 += blockDim.x) {   // final flush
        int c = min(bin_cnt[b2], BIN_CAP);
        if (c > 0) {
            int r = atomicAdd(&gcur[b2], c);
            for (int k = 0; k < c; k++)
                stage[r + k] = bin_buf[b2 * BIN_CAP + ((k + b2) & (BIN_CAP - 1))];
        }
    }
}

// ---------------- sliced per-bucket degree histogram -> deg (int) ----------------
// SPLIT blocks per bucket; LDS int hist; contiguous global int atomicAdd merge.
__global__ __launch_bounds__(512) void degree_hist(const int* __restrict__ stage,
                                                   const int* __restrict__ gcur,
                                                   int cap, int* __restrict__ deg, int n) {
    __shared__ int s0[SBW];
    int b = blockIdx.x >> 2, s = blockIdx.x & (SPLIT - 1);
    int i = threadIdx.x;
    s0[i] = 0;
    __syncthreads();
    int base  = b * cap;
    int num   = min(gcur[b] - base, cap);
    int chunk = ((num + SPLIT - 1) / SPLIT + 3) & ~3;
    int beg   = min(s * chunk, num);
    int cnt   = min(beg + chunk, num) - beg;
    const int* sp = stage + base + beg;        // 16B aligned (base,beg mult of 4)
    int cv = cnt & ~3;
    for (int k = i * 4; k < cv; k += 2048) {
        int4 v = *(const int4*)(sp + k);
        atomicAdd(&s0[v.x & (SBW - 1)], 1);
        atomicAdd(&s0[v.y & (SBW - 1)], 1);
        atomicAdd(&s0[v.z & (SBW - 1)], 1);
        atomicAdd(&s0[v.w & (SBW - 1)], 1);
    }
    if (i < (cnt & 3)) atomicAdd(&s0[sp[cv + i] & (SBW - 1)], 1);
    __syncthreads();
    int node = (b << SBSH) + i;
    if (node < n && s0[i]) atomicAdd(&deg[node], s0[i]);
}

// ---------------- layer-1 GEMM: g1 = (x @ W1) * dis, stored fp16 ----------------
// 8 lanes/node: 128B contiguous NT reads per group step (x is single-use);
// W1 staged TRANSPOSED in LDS (conflict-free); shfl_xor reduce; lane0 16B store.
__global__ __launch_bounds__(256) void gemm1(const float* __restrict__ x,
                                             const float* __restrict__ W1,
                                             const int* __restrict__ deg,
                                             __half* __restrict__ g1, int n) {
    __shared__ float w2[F_HID * F_IN];   // [f][k] transposed, 4KB
    for (int i = threadIdx.x; i < F_HID * F_IN; i += blockDim.x) {
        int f = i >> 7, k = i & (F_IN - 1);
        w2[i] = W1[k * F_HID + f];
    }
    __syncthreads();
    int t = blockIdx.x * blockDim.x + threadIdx.x;
    int node = t >> 3, l = t & 7;
    if (node >= n) return;
    const f32x4* xr = (const f32x4*)(x + (size_t)node * F_IN);
    float acc[F_HID];
#pragma unroll
    for (int f = 0; f < F_HID; f++) acc[f] = 0.0f;
#pragma unroll
    for (int it = 0; it < 4; it++) {
        int j = l + it * 8;                       // this lane's float4 index
        f32x4 v = __builtin_nontemporal_load(xr + j);
#pragma unroll
        for (int f = 0; f < F_HID; f++) {
            const float* wf = &w2[f * F_IN + j * 4];
            acc[f] += v[0] * wf[0] + v[1] * wf[1] + v[2] * wf[2] + v[3] * wf[3];
        }
    }
#pragma unroll
    for (int f = 0; f < F_HID; f++) {             // reduce across the 8 lanes
        acc[f] += __shfl_xor(acc[f], 1);
        acc[f] += __shfl_xor(acc[f], 2);
        acc[f] += __shfl_xor(acc[f], 4);
    }
    if (l == 0) {
        float d = rsqrtf((float)(deg[node] + 1));
        __half2 h[4];
#pragma unroll
        for (int p = 0; p < 4; p++) h[p] = __floats2half2_rn(acc[2 * p] * d, acc[2 * p + 1] * d);
        *(uint4*)(g1 + (size_t)node * F_HID) = *(uint4*)h;   // 16B store
    }
}

// ---------------- edge-parallel sliced bucket accumulation ----------------
__device__ __forceinline__ void gll16(const int* gsrc, int* ldst) {
    __builtin_amdgcn_global_load_lds(
        (const __attribute__((address_space(1))) void*)gsrc,
        (__attribute__((address_space(3))) void*)ldst, 16, 0, 0);
}

// stage a TILE_E-entry tile into LDS: dest = wave-uniform base + lane*16 (linear).
// stage has TILE_E ints of slack at the end (over-read garbage never processed).
__device__ __forceinline__ void stage_tile(const int* __restrict__ stage, int sb,
                                           int t, int* lbuf, int tid) {
    gll16(stage + sb + t * TILE_E + tid * 4, lbuf + ((tid >> 6) << 8));
}

// grid = B*SPLIT blocks x 512 thr. Each block: slice of a bucket's edges ->
// LDS fp32 acc[512][8] via native ds_add_f32 (8 lanes/edge, lane = feature:
// gather is one coalesced 16B group read; ds_add bank = (dst&3)*8+f, ~2-4 way).
// Edges broadcast-read 4-at-a-time via ds_read_b128. Partial acc NT-flushed
// contiguously to part[s] (no global atomics).
__global__ __launch_bounds__(512) void agg_part(const int* __restrict__ stage,
                                                const int* __restrict__ gcur, int cap,
                                                const __half* __restrict__ gin,
                                                float* __restrict__ part, size_t ss) {
    __shared__ __align__(16) float acc[SBW * F_HID];    // 16KB
    __shared__ __align__(16) int   ebuf[2 * TILE_E];    // 16KB
    int tid = threadIdx.x;
    int b = blockIdx.x >> 2, s = blockIdx.x & (SPLIT - 1);
#pragma unroll
    for (int q = 0; q < (SBW * F_HID) / 512; q++) acc[tid + q * 512] = 0.0f;
    int base  = b * cap;
    int num   = min(gcur[b] - base, cap);
    int chunk = ((num + SPLIT - 1) / SPLIT + 3) & ~3;
    int beg   = min(s * chunk, num);
    int cnt   = min(beg + chunk, num) - beg;
    int sb    = base + beg;                       // 16B aligned
    int ntile = (cnt + TILE_E - 1) / TILE_E;
    if (ntile > 0) stage_tile(stage, sb, 0, ebuf, tid);
    int g = tid >> 3, f = tid & 7;
    const __half* ginf = gin + f;
    for (int t = 0; t < ntile; t++) {
        int cur = t & 1;
        __syncthreads();                          // tile t landed (barrier drains vmcnt)
        if (t + 1 < ntile) stage_tile(stage, sb, t + 1, ebuf + ((cur ^ 1) * TILE_E), tid);
        int cnt_t = min(TILE_E, cnt - t * TILE_E);
        const int* eb = ebuf + cur * TILE_E;
        int k = 0;
        for (; k + 255 < cnt_t; k += 256) {       // group reads its 4 edges: 1 b128 broadcast
            int4 v = *(const int4*)(eb + k + 4 * g);
            float a0 = __half2float(ginf[(size_t)((unsigned)v.x >> SBSH) * F_HID]);
            float a1 = __half2float(ginf[(size_t)((unsigned)v.y >> SBSH) * F_HID]);
            float a2 = __half2float(ginf[(size_t)((unsigned)v.z >> SBSH) * F_HID]);
            float a3 = __half2float(ginf[(size_t)((unsigned)v.w >> SBSH) * F_HID]);
            atomicAdd(&acc[(v.x & (SBW - 1)) * F_HID + f], a0);   // native ds_add_f32
            atomicAdd(&acc[(v.y & (SBW - 1)) * F_HID + f], a1);
            atomicAdd(&acc[(v.z & (SBW - 1)) * F_HID + f], a2);
            atomicAdd(&acc[(v.w & (SBW - 1)) * F_HID + f], a3);
        }
        for (int k2 = k + g; k2 < cnt_t; k2 += 64) {              // tail (<256 entries)
            int v = eb[k2];
            float a = __half2float(ginf[(size_t)((unsigned)v >> SBSH) * F_HID]);
            atomicAdd(&acc[(v & (SBW - 1)) * F_HID + f], a);
        }
    }
    __syncthreads();                              // all ds_adds visible to flush
    f32x4* dst = (f32x4*)(part + s * ss + (size_t)b * (SBW * F_HID));
#pragma unroll
    for (int q = 0; q < 2; q++) {
        int idx = tid + q * 512;                  // float4 index
        f32x4 v = *(const f32x4*)&acc[idx * 4];
        __builtin_nontemporal_store(v, dst + idx);   // contiguous 16KB NT stream
    }
}

// ---------------- epilogue 1: reduce partials + bias + ReLU + xdis -> gB ----------------
__global__ __launch_bounds__(256) void ep1(const float* __restrict__ part, size_t ss,
                                           const __half* __restrict__ gA,
                                           const int* __restrict__ deg,
                                           const float* __restrict__ b1,
                                           __half* __restrict__ gB, int n) {
    int t = blockIdx.x * blockDim.x + threadIdx.x;
    if (t >= n * F_HID) return;
    int node = t >> 3, f = t & 7;
    float p0 = __builtin_nontemporal_load(part + t);
    float p1 = __builtin_nontemporal_load(part + ss + t);
    float p2 = __builtin_nontemporal_load(part + 2 * ss + t);
    float p3 = __builtin_nontemporal_load(part + 3 * ss + t);
    float sum = (p0 + p1) + (p2 + p3) + __half2float(gA[t]);      // + self-loop
    float d = rsqrtf((float)(deg[node] + 1));
    float r = fmaxf(fmaf(d, sum, b1[f]), 0.0f) * d;
    gB[t] = __float2half(r);                      // wave writes 128B contiguous
}

// ---------------- epilogue 2: reduce partials + W2/b2 -> out ----------------
__global__ __launch_bounds__(256) void ep2(const float* __restrict__ part, size_t ss,
                                           const __half* __restrict__ gB,
                                           const int* __restrict__ deg,
                                           const float* __restrict__ W2,
                                           const float* __restrict__ b2,
                                           float* __restrict__ out, int n) {
    __shared__ float w[F_HID * F_OUT];
    __shared__ float bb[F_OUT];
    if (threadIdx.x < F_HID * F_OUT) w[threadIdx.x] = W2[threadIdx.x];
    if (threadIdx.x < F_OUT) bb[threadIdx.x] = b2[threadIdx.x];
    __syncthreads();
    int node = blockIdx.x * blockDim.x + threadIdx.x;
    if (node >= n) return;
    float a[F_HID];
    uint4 hv = *(const uint4*)(gB + (size_t)node * F_HID);        // self-loop
    __half hb[F_HID]; *(uint4*)hb = hv;
#pragma unroll
    for (int j = 0; j < F_HID; j++) a[j] = __half2float(hb[j]);
#pragma unroll
    for (int s = 0; s < SPLIT; s++) {
        const f32x4* p = (const f32x4*)(part + s * ss + (size_t)node * F_HID);
        f32x4 u0 = __builtin_nontemporal_load(p);
        f32x4 u1 = __builtin_nontemporal_load(p + 1);
#pragma unroll
        for (int j = 0; j < 4; j++) { a[j] += u0[j]; a[4 + j] += u1[j]; }
    }
    float d = rsqrtf((float)(deg[node] + 1));
#pragma unroll
    for (int j = 0; j < F_HID; j++) a[j] *= d;
    float o[F_OUT];
#pragma unroll
    for (int oo = 0; oo < F_OUT; oo++) o[oo] = bb[oo];
#pragma unroll
    for (int k = 0; k < F_HID; k++)
#pragma unroll
        for (int oo = 0; oo < F_OUT; oo++)
            o[oo] = fmaf(a[k], w[k * F_OUT + oo], o[oo]);
    float4* op = (float4*)(out + (size_t)node * F_OUT);           // 64B coalesced
    op[0] = make_float4(o[0],  o[1],  o[2],  o[3]);
    op[1] = make_float4(o[4],  o[5],  o[6],  o[7]);
    op[2] = make_float4(o[8],  o[9],  o[10], o[11]);
    op[3] = make_float4(o[12], o[13], o[14], o[15]);
}

extern "C" void kernel_launch(void* const* d_in, const int* in_sizes, int n_in,
                              void* d_out, int out_size, void* d_ws, size_t ws_size,
                              hipStream_t stream) {
    const float* x  = (const float*)d_in[0];
    const int*   ei = (const int*)d_in[1];
    const float* W1 = (const float*)d_in[2];
    const float* b1 = (const float*)d_in[3];
    const float* W2 = (const float*)d_in[4];
    const float* b2 = (const float*)d_in[5];
    float* out = (float*)d_out;

    const int N = in_sizes[0] / F_IN;
    const int E = in_sizes[1] / 2;
    const int B = (N + SBW - 1) >> SBSH;   // 391 for N=200000

    // fixed bucket capacity: avg + ~6%, rounded to 256 (≈8 sigma for uniform dst)
    int avg = (E + B - 1) / B;
    int cap = (avg + avg / 16 + 255) & ~255;

    // ws (4B units): stage[B*cap + TILE_E slack] | deg[N] | gA[4N] | gB[4N]
    //                | part[SPLIT*B*SBW*F_HID] | gcur[B]
    int*    stage = (int*)d_ws;
    int*    deg   = stage + (size_t)B * cap + TILE_E;
    __half* gA    = (__half*)(deg + N);
    __half* gB    = gA + (size_t)N * F_HID;
    float*  part  = (float*)(gB + (size_t)N * F_HID);
    size_t  ss    = (size_t)B * SBW * F_HID;          // floats per slice
    int*    gcur  = (int*)(part + (size_t)SPLIT * ss);

    const int BT = 256;

    // stage_bin: 512 threads; per_block multiple of 2048 (int4 x 512 alignment)
    int per_block = ((E + 639) / 640 + 2047) & ~2047;
    int SBLK = (E + per_block - 1) / per_block;

    init_k     <<<dim3((N + BT - 1) / BT), dim3(BT), 0, stream>>>(gcur, cap, B, deg, N);
    stage_bin  <<<dim3(SBLK), dim3(512), 0, stream>>>(ei, gcur, stage, E, B, per_block);
    degree_hist<<<dim3(B * SPLIT), dim3(512), 0, stream>>>(stage, gcur, cap, deg, N);
    gemm1      <<<dim3(((size_t)N * 8 + BT - 1) / BT), dim3(BT), 0, stream>>>(x, W1, deg, gA, N);
    agg_part   <<<dim3(B * SPLIT), dim3(512), 0, stream>>>(stage, gcur, cap, gA, part, ss);
    ep1        <<<dim3(((size_t)N * 8 + BT - 1) / BT), dim3(BT), 0, stream>>>(part, ss, gA, deg, b1, gB, N);
    agg_part   <<<dim3(B * SPLIT), dim3(512), 0, stream>>>(stage, gcur, cap, gB, part, ss);
    ep2        <<<dim3((N + BT - 1) / BT), dim3(BT), 0, stream>>>(part, ss, gB, deg, W2, b2, out, N);
}

// Round 3
// 440.668 us; speedup vs baseline: 2.1434x; 1.9772x over previous
//
#include <hip/hip_runtime.h>
#include <hip/hip_fp16.h>

#define F_IN  128
#define F_HID 8
#define F_OUT 16

#define SBSH  9                 // coarse bucket = 512 consecutive dst nodes
#define SBW   (1 << SBSH)
#define MAXB  400               // supports N <= 204800
#define BIN_CAP  32             // LDS entries per bucket (stage_bin)
#define FLUSH_G  16             // flush granularity (16 ints = 64B line)

// edge_index arrives as int32 [2][E].
// Session laws: (1) scattered 4B global stores/atomics cost ~64B cross-XCD
// writeback -> all scatters are LDS-write-combined contiguous runs;
// (2) gather/scatter kernels need >=2 blocks/CU and plenty of waves;
// (3) fp16 g (3.2MB) is L2-resident -> gathers are ~200cy L2 hits; single-use
// streams (csr, x) are non-temporal; (4) per-node epilogues fuse into
// aggregates; (5) bucket regions are FIXED-CAP (avg+6%).
// R1/R2 LESSON (do not revisit without a ubench): edge-parallel aggregation
// into an LDS fp32 accumulator (global_load_lds staging + ds_add_f32) ran
// 300-350us with ALL pipes idle (VALU 3%, HBM 2%, conflicts 0, occ 66%) --
// ~15x beyond any latency model; suspect ds_add atomic-unit serialization
// (invisible to SQ_LDS_BANK_CONFLICT) and/or VGPR-12 allocation preventing
// iteration overlap. The per-node CSR gather loop below is PROVEN at 74.6us.

typedef float f32x4 __attribute__((ext_vector_type(4)));

__global__ void init_gcur(int* __restrict__ gcur, int cap, int B) {
    int b = blockIdx.x * blockDim.x + threadIdx.x;
    if (b < B) gcur[b] = b * cap;
}

// LDS write-combined binning: stage[...] = (src<<9)|(dst&511), bucket-grouped.
// 512 threads/block; int4 edge loads; bin_buf slots swizzled (pos+b)&31.
__global__ __launch_bounds__(512) void stage_bin(const int* __restrict__ ei,
                                                 int* __restrict__ gcur,
                                                 int* __restrict__ stage,
                                                 int E, int B, int per_block) {
    __shared__ int bin_cnt[MAXB];
    __shared__ int bin_buf[MAXB * BIN_CAP];   // ~51KB
    for (int i = threadIdx.x; i < B; i += blockDim.x) bin_cnt[i] = 0;
    __syncthreads();
    const bool vec = ((E & 3) == 0);
    int base = blockIdx.x * per_block;
    int end  = min(E, base + per_block);
    for (int it = base; it < end; it += (int)blockDim.x * 4) {
        int e = it + (int)threadIdx.x * 4;
        int sv[4], dv[4], m4 = 0;
        if (vec && e + 3 < end) {
            int4 s4 = *(const int4*)(ei + e);
            int4 d4 = *(const int4*)(ei + E + e);
            sv[0] = s4.x; sv[1] = s4.y; sv[2] = s4.z; sv[3] = s4.w;
            dv[0] = d4.x; dv[1] = d4.y; dv[2] = d4.z; dv[3] = d4.w;
            m4 = 4;
        } else {
            for (int q = 0; e + q < end && q < 4; q++) { sv[q] = ei[e + q]; dv[q] = ei[E + e + q]; m4++; }
        }
        for (int q = 0; q < m4; q++) {
            int b   = dv[q] >> SBSH;
            int val = (sv[q] << SBSH) | (dv[q] & (SBW - 1));
            int pos = atomicAdd(&bin_cnt[b], 1);
            if (pos < BIN_CAP) {
                bin_buf[b * BIN_CAP + ((pos + b) & (BIN_CAP - 1))] = val;
            } else {                                  // overflow (rare): direct store
                int gp = atomicAdd(&gcur[b], 1);
                stage[gp] = val;
            }
        }
        __syncthreads();
        for (int b2 = threadIdx.x; b2 < B; b2 += blockDim.x) {
            int c = min(bin_cnt[b2], BIN_CAP);
            if (c >= FLUSH_G) {
                int m = c & ~(FLUSH_G - 1);
                int r = atomicAdd(&gcur[b2], m);
                for (int k = 0; k < m; k++)
                    stage[r + k] = bin_buf[b2 * BIN_CAP + ((k + b2) & (BIN_CAP - 1))];   // contiguous run
                for (int k = m; k < c; k++)
                    bin_buf[b2 * BIN_CAP + ((k - m + b2) & (BIN_CAP - 1))] =
                        bin_buf[b2 * BIN_CAP + ((k + b2) & (BIN_CAP - 1))];
                bin_cnt[b2] = c - m;
            } else {
                bin_cnt[b2] = c;
            }
        }
        __syncthreads();
    }
    for (int b2 = threadIdx.x; b2 < B; b2 += blockDim.x) {   // final flush
        int c = min(bin_cnt[b2], BIN_CAP);
        if (c > 0) {
            int r = atomicAdd(&gcur[b2], c);
            for (int k = 0; k < c; k++)
                stage[r + k] = bin_buf[b2 * BIN_CAP + ((k + b2) & (BIN_CAP - 1))];
        }
    }
}

// one block (512 thr) per bucket: LDS per-node hist from stage -> cnt/dis,
// scan -> row_start, then scatter src into the bucket's warm CSR segment.
// fill count = gcur[b] - b*cap (no counting pre-pass).
__global__ __launch_bounds__(512) void scatter_csr(const int* __restrict__ stage,
                                                   const int* __restrict__ gcur,
                                                   int cap,
                                                   int* __restrict__ cnt,
                                                   float* __restrict__ dis,
                                                   int* __restrict__ row_start,
                                                   int* __restrict__ csr, int n) {
    __shared__ int s0[SBW], s1[SBW];
    int b  = blockIdx.x;
    int nb = b << SBSH;
    int i  = threadIdx.x;          // 0..511
    s0[i] = 0;
    __syncthreads();
    int base = b * cap;
    int num  = gcur[b] - base;
    for (int k = i; k < num; k += 512)
        atomicAdd(&s0[stage[base + k] & (SBW - 1)], 1);
    __syncthreads();
    int c = s0[i];
    if (nb + i < n) { cnt[nb + i] = c; dis[nb + i] = rsqrtf((float)(c + 1)); }
    int* src = s0; int* dst = s1;
    for (int off = 1; off < SBW; off <<= 1) {       // Hillis-Steele inclusive scan
        int v = src[i] + ((i >= off) ? src[i - off] : 0);
        dst[i] = v;
        __syncthreads();
        int* t = src; src = dst; dst = t;
    }
    int e = base + src[i] - c;                       // exclusive scan (csr shares region layout)
    if (nb + i < n) row_start[nb + i] = e;
    dst[i] = e;                                      // dst becomes the cursor array
    __syncthreads();
    for (int k = i; k < num; k += 512) {
        int v = stage[base + k];
        int pos = atomicAdd(&dst[v & (SBW - 1)], 1);
        csr[pos] = v >> SBSH;
    }
}

// ---------------- layer-1 GEMM: g1 = (x @ W1) * dis, stored fp16 ----------------
// 8 lanes/node: each group reads 128B contiguous NT per step (x single-use,
// 64B lines fully consumed per instruction); W1 staged TRANSPOSED in LDS
// (conflict-free); shfl_xor width-8 reduce; lane0 16B store.
// (harness-verified in R1/R2 runs.)
__global__ __launch_bounds__(256) void gemm1(const float* __restrict__ x,
                                             const float* __restrict__ W1,
                                             const float* __restrict__ dis,
                                             __half* __restrict__ g1, int n) {
    __shared__ float w2[F_HID * F_IN];   // [f][k] transposed, 4KB
    for (int i = threadIdx.x; i < F_HID * F_IN; i += blockDim.x) {
        int f = i >> 7, k = i & (F_IN - 1);
        w2[i] = W1[k * F_HID + f];
    }
    __syncthreads();
    int t = blockIdx.x * blockDim.x + threadIdx.x;
    int node = t >> 3, l = t & 7;
    if (node >= n) return;
    const f32x4* xr = (const f32x4*)(x + (size_t)node * F_IN);
    float acc[F_HID];
#pragma unroll
    for (int f = 0; f < F_HID; f++) acc[f] = 0.0f;
#pragma unroll
    for (int it = 0; it < 4; it++) {
        int j = l + it * 8;                       // this lane's float4 index
        f32x4 v = __builtin_nontemporal_load(xr + j);
#pragma unroll
        for (int f = 0; f < F_HID; f++) {
            const float* wf = &w2[f * F_IN + j * 4];
            acc[f] += v[0] * wf[0] + v[1] * wf[1] + v[2] * wf[2] + v[3] * wf[3];
        }
    }
#pragma unroll
    for (int f = 0; f < F_HID; f++) {             // reduce across the 8 lanes
        acc[f] += __shfl_xor(acc[f], 1);
        acc[f] += __shfl_xor(acc[f], 2);
        acc[f] += __shfl_xor(acc[f], 4);
    }
    if (l == 0) {
        float d = dis[node];
        __half2 h[4];
#pragma unroll
        for (int p = 0; p < 4; p++) h[p] = __floats2half2_rn(acc[2 * p] * d, acc[2 * p + 1] * d);
        *(uint4*)(g1 + (size_t)node * F_HID) = *(uint4*)h;   // 16B store
    }
}

// ---------------- layer-1 aggregate + bias + ReLU + xdis -> g2 (fp16) ----------------
// 8 lanes/node (lane = feature). Unroll 8: lane f loads csr[beg+j+f] (one 32B
// contiguous NT read per group covers 8 edges), __shfl(v,k,8) distributes,
// then 8 INDEPENDENT gathers in flight (2x ILP vs R0's 4, half the csr VMEM).
__global__ __launch_bounds__(256) void aggregate_relu(const int* __restrict__ csr,
                                                      const int* __restrict__ row_start,
                                                      const int* __restrict__ cnt,
                                                      const float* __restrict__ dis,
                                                      const float* __restrict__ b1,
                                                      const __half* __restrict__ gin,
                                                      __half* __restrict__ gout, int n) {
    __shared__ float bb[F_HID];
    if (threadIdx.x < F_HID) bb[threadIdx.x] = b1[threadIdx.x];
    __syncthreads();
    int t = blockIdx.x * blockDim.x + threadIdx.x;
    int node = t >> 3;
    int f = t & 7;
    if (node >= n) return;
    int beg = row_start[node];
    int c   = cnt[node];
    float acc = __half2float(gin[(size_t)node * F_HID + f]);   // self-loop
    int j = 0;
    int cm8 = c & ~7;
    for (; j < cm8; j += 8) {
        int vv = __builtin_nontemporal_load(csr + beg + j + f);  // 8 edges per group
        int s0 = __shfl(vv, 0, 8), s1 = __shfl(vv, 1, 8);
        int s2 = __shfl(vv, 2, 8), s3 = __shfl(vv, 3, 8);
        int s4 = __shfl(vv, 4, 8), s5 = __shfl(vv, 5, 8);
        int s6 = __shfl(vv, 6, 8), s7 = __shfl(vv, 7, 8);
        float a0 = __half2float(gin[(size_t)s0 * F_HID + f]);
        float a1 = __half2float(gin[(size_t)s1 * F_HID + f]);
        float a2 = __half2float(gin[(size_t)s2 * F_HID + f]);
        float a3 = __half2float(gin[(size_t)s3 * F_HID + f]);
        float a4 = __half2float(gin[(size_t)s4 * F_HID + f]);
        float a5 = __half2float(gin[(size_t)s5 * F_HID + f]);
        float a6 = __half2float(gin[(size_t)s6 * F_HID + f]);
        float a7 = __half2float(gin[(size_t)s7 * F_HID + f]);
        acc += ((a0 + a1) + (a2 + a3)) + ((a4 + a5) + (a6 + a7));
    }
    for (; j < c; j++) {
        int s = __builtin_nontemporal_load(csr + beg + j);
        acc += __half2float(gin[(size_t)s * F_HID + f]);
    }
    float d = dis[node];
    float r = fmaxf(acc * d + bb[f], 0.0f) * d;
    gout[(size_t)node * F_HID + f] = __float2half(r);          // wave writes 128B contiguous
}

// ---------------- layer-2 aggregate + W2/b2 -> out ----------------
// same unroll-8 shfl-distributed gather loop; a[k] exchanged via __shfl(w=8).
__global__ __launch_bounds__(256) void aggregate_out(const int* __restrict__ csr,
                                                     const int* __restrict__ row_start,
                                                     const int* __restrict__ cnt,
                                                     const float* __restrict__ dis,
                                                     const float* __restrict__ W2,
                                                     const float* __restrict__ b2,
                                                     const __half* __restrict__ gin,
                                                     float* __restrict__ out, int n) {
    __shared__ float w[F_HID * F_OUT];
    __shared__ float bb[F_OUT];
    if (threadIdx.x < F_HID * F_OUT) w[threadIdx.x] = W2[threadIdx.x];
    if (threadIdx.x < F_OUT) bb[threadIdx.x] = b2[threadIdx.x];
    __syncthreads();
    int t = blockIdx.x * blockDim.x + threadIdx.x;
    int node = t >> 3;
    int f = t & 7;
    if (node >= n) return;
    int beg = row_start[node];
    int c   = cnt[node];
    float acc = __half2float(gin[(size_t)node * F_HID + f]);   // self-loop
    int j = 0;
    int cm8 = c & ~7;
    for (; j < cm8; j += 8) {
        int vv = __builtin_nontemporal_load(csr + beg + j + f);
        int s0 = __shfl(vv, 0, 8), s1 = __shfl(vv, 1, 8);
        int s2 = __shfl(vv, 2, 8), s3 = __shfl(vv, 3, 8);
        int s4 = __shfl(vv, 4, 8), s5 = __shfl(vv, 5, 8);
        int s6 = __shfl(vv, 6, 8), s7 = __shfl(vv, 7, 8);
        float a0 = __half2float(gin[(size_t)s0 * F_HID + f]);
        float a1 = __half2float(gin[(size_t)s1 * F_HID + f]);
        float a2 = __half2float(gin[(size_t)s2 * F_HID + f]);
        float a3 = __half2float(gin[(size_t)s3 * F_HID + f]);
        float a4 = __half2float(gin[(size_t)s4 * F_HID + f]);
        float a5 = __half2float(gin[(size_t)s5 * F_HID + f]);
        float a6 = __half2float(gin[(size_t)s6 * F_HID + f]);
        float a7 = __half2float(gin[(size_t)s7 * F_HID + f]);
        acc += ((a0 + a1) + (a2 + a3)) + ((a4 + a5) + (a6 + a7));
    }
    for (; j < c; j++) {
        int s = __builtin_nontemporal_load(csr + beg + j);
        acc += __half2float(gin[(size_t)s * F_HID + f]);
    }
    float a_self = acc * dis[node];                            // agg2[node][f]
    float o0 = bb[2 * f], o1 = bb[2 * f + 1];
#pragma unroll
    for (int k = 0; k < 8; k++) {
        float ak = __shfl(a_self, k, 8);                       // group-wide exchange
        o0 += ak * w[k * F_OUT + 2 * f];
        o1 += ak * w[k * F_OUT + 2 * f + 1];
    }
    *(float2*)(out + (size_t)node * F_OUT + 2 * f) = make_float2(o0, o1);
}

extern "C" void kernel_launch(void* const* d_in, const int* in_sizes, int n_in,
                              void* d_out, int out_size, void* d_ws, size_t ws_size,
                              hipStream_t stream) {
    const float* x  = (const float*)d_in[0];
    const int*   ei = (const int*)d_in[1];
    const float* W1 = (const float*)d_in[2];
    const float* b1 = (const float*)d_in[3];
    const float* W2 = (const float*)d_in[4];
    const float* b2 = (const float*)d_in[5];
    float* out = (float*)d_out;

    const int N = in_sizes[0] / F_IN;
    const int E = in_sizes[1] / 2;
    const int B = (N + SBW - 1) >> SBSH;   // 391 for N=200000

    // fixed bucket capacity: avg + ~6%, rounded to 256 (≈8 sigma for uniform dst)
    int avg = (E + B - 1) / B;
    int cap = (avg + avg / 16 + 255) & ~255;

    // ws (4B units): stage[B*cap] | csr[B*cap] | dis[N] | gA[4N] | gB[4N]
    //                | cnt[N] | row_start[N] | gcur[B]
    int*    stage     = (int*)d_ws;
    int*    csr       = stage + (size_t)B * cap;
    float*  dis       = (float*)(csr + (size_t)B * cap);
    __half* gA        = (__half*)(dis + N);
    __half* gB        = (__half*)((int*)gA + (size_t)N * 4);
    int*    cnt       = (int*)gB + (size_t)N * 4;
    int*    row_start = cnt + N;
    int*    gcur      = row_start + N;

    const int BT = 256;
    dim3 thr(BT);
    dim3 blkA(((size_t)N * F_HID + BT - 1) / BT);

    // stage_bin: 512 threads; per_block multiple of 2048 (int4 x 512 alignment)
    int per_block = ((E + 639) / 640 + 2047) & ~2047;
    int SBLK = (E + per_block - 1) / per_block;

    init_gcur     <<<dim3((B + BT - 1) / BT), thr, 0, stream>>>(gcur, cap, B);
    stage_bin     <<<dim3(SBLK), dim3(512), 0, stream>>>(ei, gcur, stage, E, B, per_block);
    scatter_csr   <<<dim3(B),   dim3(512), 0, stream>>>(stage, gcur, cap, cnt, dis, row_start, csr, N);
    gemm1         <<<blkA, thr, 0, stream>>>(x, W1, dis, gA, N);
    aggregate_relu<<<blkA, thr, 0, stream>>>(csr, row_start, cnt, dis, b1, gA, gB, N);
    aggregate_out <<<blkA, thr, 0, stream>>>(csr, row_start, cnt, dis, W2, b2, gB, out, N);
}

// Round 4
// 435.423 us; speedup vs baseline: 2.1693x; 1.0120x over previous
//
#include <hip/hip_runtime.h>
#include <hip/hip_fp16.h>

#define F_IN  128
#define F_HID 8
#define F_OUT 16

#define SBSH  9                 // coarse bucket = 512 consecutive dst nodes
#define SBW   (1 << SBSH)
#define MAXB  400               // supports N <= 204800
#define BIN_CAP  32             // LDS entries per bucket (stage_bin)
#define FLUSH_G  16             // flush granularity (16 ints = 64B line)

// edge_index arrives as int32 [2][E].
// Session laws: (1) scattered 4B global stores/atomics cost ~64B cross-XCD
// writeback -> all scatters are LDS-write-combined contiguous runs;
// (2) gather/scatter kernels need >=2 blocks/CU and plenty of waves;
// (3) fp16 g (3.2MB) is L2-resident -> gathers are ~200cy L2 hits; single-use
// streams (csr, x) are non-temporal; (4) per-node epilogues fuse into
// aggregates; (5) bucket regions are FIXED-CAP (avg+6%).
// R1/R2 LESSON (do not revisit without a ubench): edge-parallel aggregation
// into an LDS fp32 accumulator (global_load_lds staging + ds_add_f32) ran
// 300-350us with ALL pipes idle -- ~15x beyond any latency model.
// R3 LESSON: unroll-8 shfl-distributed csr (8 lanes/node) did NOT speed the
// aggregate (still ~74us): the limit is in-flight LINES per wave, not csr
// instruction count. R4: 4 lanes/node + half2 -> 16 nodes/wave, 128 lines
// in flight per unroll-8 batch (2x MLP), half the instructions per edge.

typedef float f32x4 __attribute__((ext_vector_type(4)));

__global__ void init_gcur(int* __restrict__ gcur, int cap, int B) {
    int b = blockIdx.x * blockDim.x + threadIdx.x;
    if (b < B) gcur[b] = b * cap;
}

// LDS write-combined binning: stage[...] = (src<<9)|(dst&511), bucket-grouped.
// 512 threads/block; int4 edge loads; bin_buf slots swizzled (pos+b)&31.
__global__ __launch_bounds__(512) void stage_bin(const int* __restrict__ ei,
                                                 int* __restrict__ gcur,
                                                 int* __restrict__ stage,
                                                 int E, int B, int per_block) {
    __shared__ int bin_cnt[MAXB];
    __shared__ int bin_buf[MAXB * BIN_CAP];   // ~51KB
    for (int i = threadIdx.x; i < B; i += blockDim.x) bin_cnt[i] = 0;
    __syncthreads();
    const bool vec = ((E & 3) == 0);
    int base = blockIdx.x * per_block;
    int end  = min(E, base + per_block);
    for (int it = base; it < end; it += (int)blockDim.x * 4) {
        int e = it + (int)threadIdx.x * 4;
        int sv[4], dv[4], m4 = 0;
        if (vec && e + 3 < end) {
            int4 s4 = *(const int4*)(ei + e);
            int4 d4 = *(const int4*)(ei + E + e);
            sv[0] = s4.x; sv[1] = s4.y; sv[2] = s4.z; sv[3] = s4.w;
            dv[0] = d4.x; dv[1] = d4.y; dv[2] = d4.z; dv[3] = d4.w;
            m4 = 4;
        } else {
            for (int q = 0; e + q < end && q < 4; q++) { sv[q] = ei[e + q]; dv[q] = ei[E + e + q]; m4++; }
        }
        for (int q = 0; q < m4; q++) {
            int b   = dv[q] >> SBSH;
            int val = (sv[q] << SBSH) | (dv[q] & (SBW - 1));
            int pos = atomicAdd(&bin_cnt[b], 1);
            if (pos < BIN_CAP) {
                bin_buf[b * BIN_CAP + ((pos + b) & (BIN_CAP - 1))] = val;
            } else {                                  // overflow (rare): direct store
                int gp = atomicAdd(&gcur[b], 1);
                stage[gp] = val;
            }
        }
        __syncthreads();
        for (int b2 = threadIdx.x; b2 < B; b2 += blockDim.x) {
            int c = min(bin_cnt[b2], BIN_CAP);
            if (c >= FLUSH_G) {
                int m = c & ~(FLUSH_G - 1);
                int r = atomicAdd(&gcur[b2], m);
                for (int k = 0; k < m; k++)
                    stage[r + k] = bin_buf[b2 * BIN_CAP + ((k + b2) & (BIN_CAP - 1))];   // contiguous run
                for (int k = m; k < c; k++)
                    bin_buf[b2 * BIN_CAP + ((k - m + b2) & (BIN_CAP - 1))] =
                        bin_buf[b2 * BIN_CAP + ((k + b2) & (BIN_CAP - 1))];
                bin_cnt[b2] = c - m;
            } else {
                bin_cnt[b2] = c;
            }
        }
        __syncthreads();
    }
    for (int b2 = threadIdx.x; b2 < B; b2 += blockDim.x) {   // final flush
        int c = min(bin_cnt[b2], BIN_CAP);
        if (c > 0) {
            int r = atomicAdd(&gcur[b2], c);
            for (int k = 0; k < c; k++)
                stage[r + k] = bin_buf[b2 * BIN_CAP + ((k + b2) & (BIN_CAP - 1))];
        }
    }
}

// one block (1024 thr) per bucket: LDS per-node hist from stage -> cnt/dis,
// scan -> row_start, then scatter src into the bucket's warm CSR segment.
// 1024 threads (R4): grid is 391 blocks (~1.5/CU) so makespan = 2 x block
// time; doubling threads halves block time at identical work.
__global__ __launch_bounds__(1024) void scatter_csr(const int* __restrict__ stage,
                                                    const int* __restrict__ gcur,
                                                    int cap,
                                                    int* __restrict__ cnt,
                                                    float* __restrict__ dis,
                                                    int* __restrict__ row_start,
                                                    int* __restrict__ csr, int n) {
    __shared__ int s0[SBW], s1[SBW];
    int b  = blockIdx.x;
    int nb = b << SBSH;
    int i  = threadIdx.x;          // 0..1023
    if (i < SBW) s0[i] = 0;
    __syncthreads();
    int base = b * cap;
    int num  = gcur[b] - base;
    for (int k = i; k < num; k += 1024)
        atomicAdd(&s0[stage[base + k] & (SBW - 1)], 1);
    __syncthreads();
    int c = (i < SBW) ? s0[i] : 0;
    if (i < SBW && nb + i < n) { cnt[nb + i] = c; dis[nb + i] = rsqrtf((float)(c + 1)); }
    int* src = s0; int* dst = s1;
    for (int off = 1; off < SBW; off <<= 1) {       // Hillis-Steele inclusive scan
        if (i < SBW) dst[i] = src[i] + ((i >= off) ? src[i - off] : 0);
        __syncthreads();
        int* t = src; src = dst; dst = t;
    }
    if (i < SBW) {
        int e = base + src[i] - c;                   // exclusive scan (csr shares region layout)
        if (nb + i < n) row_start[nb + i] = e;
        dst[i] = e;                                  // dst becomes the cursor array
    }
    __syncthreads();
    for (int k = i; k < num; k += 1024) {
        int v = stage[base + k];
        int pos = atomicAdd(&dst[v & (SBW - 1)], 1);
        csr[pos] = v >> SBSH;
    }
}

// ---------------- layer-1 GEMM: g1 = (x @ W1) * dis, stored fp16 ----------------
// 8 lanes/node: each group reads 128B contiguous NT per step (x single-use,
// 64B lines fully consumed per instruction); W1 staged TRANSPOSED in LDS
// (conflict-free); shfl_xor width-8 reduce; lane0 16B store. (verified R1-R3)
__global__ __launch_bounds__(256) void gemm1(const float* __restrict__ x,
                                             const float* __restrict__ W1,
                                             const float* __restrict__ dis,
                                             __half* __restrict__ g1, int n) {
    __shared__ float w2[F_HID * F_IN];   // [f][k] transposed, 4KB
    for (int i = threadIdx.x; i < F_HID * F_IN; i += blockDim.x) {
        int f = i >> 7, k = i & (F_IN - 1);
        w2[i] = W1[k * F_HID + f];
    }
    __syncthreads();
    int t = blockIdx.x * blockDim.x + threadIdx.x;
    int node = t >> 3, l = t & 7;
    if (node >= n) return;
    const f32x4* xr = (const f32x4*)(x + (size_t)node * F_IN);
    float acc[F_HID];
#pragma unroll
    for (int f = 0; f < F_HID; f++) acc[f] = 0.0f;
#pragma unroll
    for (int it = 0; it < 4; it++) {
        int j = l + it * 8;                       // this lane's float4 index
        f32x4 v = __builtin_nontemporal_load(xr + j);
#pragma unroll
        for (int f = 0; f < F_HID; f++) {
            const float* wf = &w2[f * F_IN + j * 4];
            acc[f] += v[0] * wf[0] + v[1] * wf[1] + v[2] * wf[2] + v[3] * wf[3];
        }
    }
#pragma unroll
    for (int f = 0; f < F_HID; f++) {             // reduce across the 8 lanes
        acc[f] += __shfl_xor(acc[f], 1);
        acc[f] += __shfl_xor(acc[f], 2);
        acc[f] += __shfl_xor(acc[f], 4);
    }
    if (l == 0) {
        float d = dis[node];
        __half2 h[4];
#pragma unroll
        for (int p = 0; p < 4; p++) h[p] = __floats2half2_rn(acc[2 * p] * d, acc[2 * p + 1] * d);
        *(uint4*)(g1 + (size_t)node * F_HID) = *(uint4*)h;   // 16B store
    }
}

// ---------------- layer-1 aggregate + bias + ReLU + xdis -> g2 (fp16) ----------------
// R4: 4 lanes/node, lane l owns features {2l,2l+1} as one half2 (4B load).
// 16 nodes/wave -> each gather instr touches 16 lines; unroll 8 -> 128 lines
// in flight per wave. csr: two NT 4B loads per lane cover 8 edges, shfl(w=4).
__global__ __launch_bounds__(256) void aggregate_relu(const int* __restrict__ csr,
                                                      const int* __restrict__ row_start,
                                                      const int* __restrict__ cnt,
                                                      const float* __restrict__ dis,
                                                      const float* __restrict__ b1,
                                                      const __half* __restrict__ gin,
                                                      __half* __restrict__ gout, int n) {
    int t = blockIdx.x * blockDim.x + threadIdx.x;
    int node = t >> 2;
    int l = t & 3;
    if (node >= n) return;
    const __half2* g2 = (const __half2*)gin;      // half2 index = src*4 + l
    int beg = row_start[node];
    int c   = cnt[node];
    float2 acc = __half22float2(g2[(unsigned)node * 4 + l]);   // self-loop
    int j = 0;
    int cm8 = c & ~7;
    for (; j < cm8; j += 8) {
        int va = __builtin_nontemporal_load(csr + beg + j + l);
        int vb = __builtin_nontemporal_load(csr + beg + j + 4 + l);
        int s0 = __shfl(va, 0, 4), s1 = __shfl(va, 1, 4);
        int s2 = __shfl(va, 2, 4), s3 = __shfl(va, 3, 4);
        int s4 = __shfl(vb, 0, 4), s5 = __shfl(vb, 1, 4);
        int s6 = __shfl(vb, 2, 4), s7 = __shfl(vb, 3, 4);
        __half2 h0 = g2[(unsigned)s0 * 4 + l];    // 8 independent 4B gathers
        __half2 h1 = g2[(unsigned)s1 * 4 + l];
        __half2 h2 = g2[(unsigned)s2 * 4 + l];
        __half2 h3 = g2[(unsigned)s3 * 4 + l];
        __half2 h4 = g2[(unsigned)s4 * 4 + l];
        __half2 h5 = g2[(unsigned)s5 * 4 + l];
        __half2 h6 = g2[(unsigned)s6 * 4 + l];
        __half2 h7 = g2[(unsigned)s7 * 4 + l];
        float2 f0 = __half22float2(h0), f1 = __half22float2(h1);
        float2 f2 = __half22float2(h2), f3 = __half22float2(h3);
        float2 f4 = __half22float2(h4), f5 = __half22float2(h5);
        float2 f6 = __half22float2(h6), f7 = __half22float2(h7);
        acc.x += ((f0.x + f1.x) + (f2.x + f3.x)) + ((f4.x + f5.x) + (f6.x + f7.x));
        acc.y += ((f0.y + f1.y) + (f2.y + f3.y)) + ((f4.y + f5.y) + (f6.y + f7.y));
    }
    for (; j < c; j++) {
        int s = __builtin_nontemporal_load(csr + beg + j);
        float2 a = __half22float2(g2[(unsigned)s * 4 + l]);
        acc.x += a.x; acc.y += a.y;
    }
    float d = dis[node];
    float2 bv = *(const float2*)(b1 + 2 * l);
    float rx = fmaxf(fmaf(acc.x, d, bv.x), 0.0f) * d;
    float ry = fmaxf(fmaf(acc.y, d, bv.y), 0.0f) * d;
    ((__half2*)gout)[(unsigned)node * 4 + l] = __floats2half2_rn(rx, ry);  // 256B/wave
}

// ---------------- layer-2 aggregate + W2/b2 -> out ----------------
// same 4-lane half2 gather loop; epilogue: lane l computes outputs 4l..4l+3,
// a[k] exchanged via shfl(w=4); W2/b2 read directly (L1-hot, epilogue-only).
__global__ __launch_bounds__(256) void aggregate_out(const int* __restrict__ csr,
                                                     const int* __restrict__ row_start,
                                                     const int* __restrict__ cnt,
                                                     const float* __restrict__ dis,
                                                     const float* __restrict__ W2,
                                                     const float* __restrict__ b2,
                                                     const __half* __restrict__ gin,
                                                     float* __restrict__ out, int n) {
    int t = blockIdx.x * blockDim.x + threadIdx.x;
    int node = t >> 2;
    int l = t & 3;
    if (node >= n) return;
    const __half2* g2 = (const __half2*)gin;
    int beg = row_start[node];
    int c   = cnt[node];
    float2 acc = __half22float2(g2[(unsigned)node * 4 + l]);   // self-loop
    int j = 0;
    int cm8 = c & ~7;
    for (; j < cm8; j += 8) {
        int va = __builtin_nontemporal_load(csr + beg + j + l);
        int vb = __builtin_nontemporal_load(csr + beg + j + 4 + l);
        int s0 = __shfl(va, 0, 4), s1 = __shfl(va, 1, 4);
        int s2 = __shfl(va, 2, 4), s3 = __shfl(va, 3, 4);
        int s4 = __shfl(vb, 0, 4), s5 = __shfl(vb, 1, 4);
        int s6 = __shfl(vb, 2, 4), s7 = __shfl(vb, 3, 4);
        __half2 h0 = g2[(unsigned)s0 * 4 + l];
        __half2 h1 = g2[(unsigned)s1 * 4 + l];
        __half2 h2 = g2[(unsigned)s2 * 4 + l];
        __half2 h3 = g2[(unsigned)s3 * 4 + l];
        __half2 h4 = g2[(unsigned)s4 * 4 + l];
        __half2 h5 = g2[(unsigned)s5 * 4 + l];
        __half2 h6 = g2[(unsigned)s6 * 4 + l];
        __half2 h7 = g2[(unsigned)s7 * 4 + l];
        float2 f0 = __half22float2(h0), f1 = __half22float2(h1);
        float2 f2 = __half22float2(h2), f3 = __half22float2(h3);
        float2 f4 = __half22float2(h4), f5 = __half22float2(h5);
        float2 f6 = __half22float2(h6), f7 = __half22float2(h7);
        acc.x += ((f0.x + f1.x) + (f2.x + f3.x)) + ((f4.x + f5.x) + (f6.x + f7.x));
        acc.y += ((f0.y + f1.y) + (f2.y + f3.y)) + ((f4.y + f5.y) + (f6.y + f7.y));
    }
    for (; j < c; j++) {
        int s = __builtin_nontemporal_load(csr + beg + j);
        float2 a = __half22float2(g2[(unsigned)s * 4 + l]);
        acc.x += a.x; acc.y += a.y;
    }
    float d = dis[node];
    float ax = acc.x * d, ay = acc.y * d;         // a[2l], a[2l+1]
    float4 o = ((const float4*)b2)[l];            // outputs 4l..4l+3
#pragma unroll
    for (int s = 0; s < 4; s++) {
        float axs = __shfl(ax, s, 4);             // a[2s]
        float ays = __shfl(ay, s, 4);             // a[2s+1]
        float4 w0 = ((const float4*)W2)[(2 * s) * 4 + l];       // W2[2s][4l..4l+3]
        float4 w1 = ((const float4*)W2)[(2 * s + 1) * 4 + l];   // W2[2s+1][4l..4l+3]
        o.x = fmaf(axs, w0.x, fmaf(ays, w1.x, o.x));
        o.y = fmaf(axs, w0.y, fmaf(ays, w1.y, o.y));
        o.z = fmaf(axs, w0.z, fmaf(ays, w1.z, o.z));
        o.w = fmaf(axs, w0.w, fmaf(ays, w1.w, o.w));
    }
    *(float4*)(out + (size_t)node * F_OUT + 4 * l) = o;         // 1KB/wave contiguous
}

extern "C" void kernel_launch(void* const* d_in, const int* in_sizes, int n_in,
                              void* d_out, int out_size, void* d_ws, size_t ws_size,
                              hipStream_t stream) {
    const float* x  = (const float*)d_in[0];
    const int*   ei = (const int*)d_in[1];
    const float* W1 = (const float*)d_in[2];
    const float* b1 = (const float*)d_in[3];
    const float* W2 = (const float*)d_in[4];
    const float* b2 = (const float*)d_in[5];
    float* out = (float*)d_out;

    const int N = in_sizes[0] / F_IN;
    const int E = in_sizes[1] / 2;
    const int B = (N + SBW - 1) >> SBSH;   // 391 for N=200000

    // fixed bucket capacity: avg + ~6%, rounded to 256 (≈8 sigma for uniform dst)
    int avg = (E + B - 1) / B;
    int cap = (avg + avg / 16 + 255) & ~255;

    // ws (4B units): stage[B*cap] | csr[B*cap] | dis[N] | gA[4N] | gB[4N]
    //                | cnt[N] | row_start[N] | gcur[B]
    int*    stage     = (int*)d_ws;
    int*    csr       = stage + (size_t)B * cap;
    float*  dis       = (float*)(csr + (size_t)B * cap);
    __half* gA        = (__half*)(dis + N);
    __half* gB        = (__half*)((int*)gA + (size_t)N * 4);
    int*    cnt       = (int*)gB + (size_t)N * 4;
    int*    row_start = cnt + N;
    int*    gcur      = row_start + N;

    const int BT = 256;
    dim3 thr(BT);
    dim3 blkG(((size_t)N * 8 + BT - 1) / BT);    // gemm1: 8 lanes/node
    dim3 blkA(((size_t)N * 4 + BT - 1) / BT);    // aggregates: 4 lanes/node

    // stage_bin: 512 threads; per_block multiple of 2048 (int4 x 512 alignment)
    int per_block = ((E + 639) / 640 + 2047) & ~2047;
    int SBLK = (E + per_block - 1) / per_block;

    init_gcur     <<<dim3((B + BT - 1) / BT), thr, 0, stream>>>(gcur, cap, B);
    stage_bin     <<<dim3(SBLK), dim3(512), 0, stream>>>(ei, gcur, stage, E, B, per_block);
    scatter_csr   <<<dim3(B),   dim3(1024), 0, stream>>>(stage, gcur, cap, cnt, dis, row_start, csr, N);
    gemm1         <<<blkG, thr, 0, stream>>>(x, W1, dis, gA, N);
    aggregate_relu<<<blkA, thr, 0, stream>>>(csr, row_start, cnt, dis, b1, gA, gB, N);
    aggregate_out <<<blkA, thr, 0, stream>>>(csr, row_start, cnt, dis, W2, b2, gB, out, N);
}